// Round 9
// baseline (372.554 us; speedup 1.0000x reference)
//
#include <hip/hip_runtime.h>
#include <stdint.h>

// ---- types ----
typedef __attribute__((ext_vector_type(8))) short bf16x8;     // 8 x bf16 = 4 VGPR
typedef __attribute__((ext_vector_type(4))) float f32x4;
typedef __attribute__((ext_vector_type(4))) unsigned short us4;
typedef __attribute__((ext_vector_type(8))) unsigned short us8;

// fp32 -> bf16 round-to-nearest-even
static __device__ __forceinline__ unsigned short f2bf(float f) {
  union { float f; unsigned u; } c; c.f = f;
  unsigned r = c.u + 0x7fffu + ((c.u >> 16) & 1u);
  return (unsigned short)(r >> 16);
}

// async global->LDS, 16B per lane. LDS dest is WAVE-UNIFORM base; HW writes
// lane l at base + l*16. Global src is per-lane.
static __device__ __forceinline__ void gl_lds16(const unsigned short* g, unsigned short* l) {
  __builtin_amdgcn_global_load_lds(
      (const __attribute__((address_space(1))) unsigned int*)g,
      (__attribute__((address_space(3))) unsigned int*)l, 16, 0, 0);
}

// Problem constants: x (r=64, i=256, n=2, E=768), h=12, d=64.
// tokens T = 32768 in (r,i,n) order (n fastest); scores K-dim = r*d = 4096; hn = 24.
#define LDP 80   // padded LDS row for the reg-staged kernels (conflict-free, measured 0)

// ======================================================================
// T4 counted-vmcnt double-buffered GEMM core (r8-proven).
//   prologue: stage(buf0)
//   loop:     stage(buf^1, t+1); s_waitcnt vmcnt(8); s_barrier;   // t ready,
//             compute(buf);      s_barrier;                       // t+1 in flight
//   epilogue: vmcnt(0); barrier; compute(last)
// C(128x128) += A(128xK) * B^T (B stored [col][k]). 256 thr = 4 waves (2x2),
// each wave 64x64 = 4x4 frags of 16x16x32. BK=64.
// LDS: 2 bufs x [128][64] bf16 per operand (64KB). XOR swizzle (rule #21):
// LDS unit u of row holds global column-chunk u ^ (row&7); the fragment read
// applies the same XOR. Conflicts measured 0.
// ======================================================================
__device__ __forceinline__ void stage8(
    const unsigned short* __restrict__ Ag, int lda,
    const unsigned short* __restrict__ Bg, int ldb, int kt,
    unsigned short* As, unsigned short* Bs, int tid, int wid)
{
#pragma unroll
  for (int c = 0; c < 4; ++c) {          // 1024 16B-chunks/tile, 4 rounds
    int chunk = c * 256 + tid;
    int row = chunk >> 3, u = chunk & 7;
    int ch = u ^ (row & 7);              // inverse-swizzled source column chunk
    gl_lds16(Ag + row * lda + kt + ch * 8, As + ((c * 256 + wid * 64) << 3));
    gl_lds16(Bg + row * ldb + kt + ch * 8, Bs + ((c * 256 + wid * 64) << 3));
  }
}

__device__ __forceinline__ void compute64(
    const unsigned short* As, const unsigned short* Bs, f32x4 acc[4][4],
    int wr, int wc, int lr, int kg, int l7)
{
#pragma unroll
  for (int ks = 0; ks < 2; ++ks) {
    bf16x8 af[4], bfr[4];
    int u = (ks * 4 + kg) ^ l7;          // swizzled read unit
#pragma unroll
    for (int mi = 0; mi < 4; ++mi)
      af[mi] = *reinterpret_cast<const bf16x8*>(As + (wr*64 + mi*16 + lr) * 64 + u * 8);
#pragma unroll
    for (int ni = 0; ni < 4; ++ni)
      bfr[ni] = *reinterpret_cast<const bf16x8*>(Bs + (wc*64 + ni*16 + lr) * 64 + u * 8);
#pragma unroll
    for (int mi = 0; mi < 4; ++mi)
#pragma unroll
      for (int ni = 0; ni < 4; ++ni)
        acc[mi][ni] = __builtin_amdgcn_mfma_f32_16x16x32_bf16(af[mi], bfr[ni], acc[mi][ni], 0, 0, 0);
  }
}

__device__ __forceinline__ void gemm_core(
    const unsigned short* __restrict__ Ag, int lda,
    const unsigned short* __restrict__ Bg, int ldb,
    int K, unsigned short* As, unsigned short* Bs, f32x4 acc[4][4])
{
  const int tid  = threadIdx.x;
  const int lane = tid & 63;
  const int wid  = tid >> 6;
  const int wr = wid >> 1, wc = wid & 1;
  const int lr = lane & 15, kg = lane >> 4;
  const int l7 = lane & 7;

  const int nt = K >> 6;
  stage8(Ag, lda, Bg, ldb, 0, As, Bs, tid, wid);
  int cur = 0;
  for (int t = 0; t < nt - 1; ++t) {
    stage8(Ag, lda, Bg, ldb, (t + 1) << 6,
           As + (cur ^ 1) * 8192, Bs + (cur ^ 1) * 8192, tid, wid);
    asm volatile("s_waitcnt vmcnt(8)" ::: "memory");  // tile t done; t+1 in flight
    __builtin_amdgcn_s_barrier();
    compute64(As + cur * 8192, Bs + cur * 8192, acc, wr, wc, lr, kg, l7);
    __builtin_amdgcn_s_barrier();                     // buf free before overwrite
    cur ^= 1;
  }
  asm volatile("s_waitcnt vmcnt(0)" ::: "memory");
  __builtin_amdgcn_s_barrier();
  compute64(As + cur * 8192, Bs + cur * 8192, acc, wr, wc, lr, kg, l7);
}

#define ACC_ZERO(acc) do { \
  f32x4 z = {0.f, 0.f, 0.f, 0.f}; \
  for (int a_ = 0; a_ < 4; ++a_) for (int b_ = 0; b_ < 4; ++b_) acc[a_][b_] = z; } while (0)

#define EPI_VARS \
  int tid = threadIdx.x, lane = tid & 63, wid = tid >> 6; \
  int wr = wid >> 1, wc = wid & 1, lr = lane & 15, kg = lane >> 4; (void)wr; (void)wc;

#define GEMM_LDS \
  __shared__ unsigned short As[2 * 128 * 64], Bs[2 * 128 * 64];

// ======================================================================
// Kernels
// ======================================================================

// x fp32 -> bf16, 4 elems/thread. grid 24576x256 covers 25165824 exactly.
__global__ __launch_bounds__(256) void k_cvt_x(const float* __restrict__ x,
                                               unsigned short* __restrict__ xb) {
  int i = blockIdx.x * 256 + threadIdx.x;
  f32x4 f = reinterpret_cast<const f32x4*>(x)[i];
  us4 o = { f2bf(f[0]), f2bf(f[1]), f2bf(f[2]), f2bf(f[3]) };
  reinterpret_cast<us4*>(xb)[i] = o;
}

// Transposed bf16 weights wT[col][k] (q-part pre-scaled by 1/64), woT[col][k],
// fused bias bqkv (q-part scaled). grid 9225x256 = 2361600 exactly.
__global__ __launch_bounds__(256) void k_cvt_w(
    const float* __restrict__ Wq, const float* __restrict__ Wk, const float* __restrict__ Wv,
    const float* __restrict__ Wo, const float* __restrict__ bq, const float* __restrict__ bk,
    const float* __restrict__ bv, unsigned short* __restrict__ wT,
    unsigned short* __restrict__ woT, float* __restrict__ bqkv)
{
  const float qs = 1.0f / 64.0f;  // d^-0.5 / sqrt(r) = (1/8)/8
  int o = blockIdx.x * 256 + threadIdx.x;
  if (o < 2304 * 768) {
    int col = o / 768, k = o % 768;
    float v;
    if (col < 768)       v = Wq[k * 768 + col] * qs;
    else if (col < 1536) v = Wk[k * 768 + col - 768];
    else                 v = Wv[k * 768 + col - 1536];
    wT[o] = f2bf(v);
  } else if (o < 2304 * 768 + 768 * 768) {
    int o2 = o - 2304 * 768;
    int col = o2 / 768, k = o2 % 768;
    woT[o2] = f2bf(Wo[k * 768 + col]);
  } else {
    int o3 = o - (2304 * 768 + 768 * 768);
    float v = (o3 < 768) ? bq[o3] * qs : (o3 < 1536 ? bk[o3 - 768] : bv[o3 - 1536]);
    bqkv[o3] = v;
  }
}

// QKV projection: qkvb[t][0..2303] = bf16(x@[Wq|Wk|Wv]+b). Clean coalesced
// epilogue + bijective XCD swizzle: XCD x owns bm in [32x, 32(x+1)) so each
// xb row-tile stays in ONE XCD's L2 across its 18-bn run. grid 4608.
__global__ __launch_bounds__(256) void k_gemm_qkv(
    const unsigned short* __restrict__ xb, const unsigned short* __restrict__ wT,
    const float* __restrict__ bqkv, unsigned short* __restrict__ qkvb)
{
  GEMM_LDS;
  int b0 = blockIdx.x;
  int bx = (b0 & 7) * 576 + (b0 >> 3);     // bijective (4608 = 8 * 576)
  int bn = bx % 18, bm = bx / 18;
  f32x4 acc[4][4]; ACC_ZERO(acc);
  gemm_core(xb + (size_t)bm * 128 * 768, 768, wT + (size_t)bn * 128 * 768, 768, 768, As, Bs, acc);
  EPI_VARS;
#pragma unroll
  for (int mi = 0; mi < 4; ++mi)
#pragma unroll
    for (int ni = 0; ni < 4; ++ni) {
      int col = bn * 128 + wc * 64 + ni * 16 + lr;
      float bias = bqkv[col];
#pragma unroll
      for (int e = 0; e < 4; ++e) {
        int row = bm * 128 + wr * 64 + mi * 16 + kg * 4 + e;   // token
        qkvb[(size_t)row * 2304 + col] = f2bf(acc[mi][ni][e] + bias);
      }
    }
}

// Repack v -> V[h][n][rr*64+dd][j=i] (j-contiguous) via LDS 64x64 transpose.
// Reads qkvb directly. grid 24*64*4 = 6144 blocks.
__global__ __launch_bounds__(256) void k_repack_v(
    const unsigned short* __restrict__ qkvb, unsigned short* __restrict__ V)
{
  __shared__ unsigned short lds[64 * LDP];
  int bx = blockIdx.x;
  int jt = bx & 3, rr = (bx >> 2) & 63, hn = bx >> 8;
  int h = hn >> 1, nn = hn & 1;
  int t = threadIdx.x;
  int j = t >> 3, ch = t & 7;
#pragma unroll
  for (int p = 0; p < 2; ++p) {
    int jj = p * 32 + j;
    us8 v = *reinterpret_cast<const us8*>(
        qkvb + ((size_t)((rr * 256 + jt * 64 + jj) * 2 + nn)) * 2304 + 1536 + h * 64 + ch * 8);
#pragma unroll
    for (int e = 0; e < 8; ++e) lds[(ch * 8 + e) * LDP + jj] = v[e];
  }
  __syncthreads();
  int dd = t >> 2, cj = t & 3;
  size_t ob = ((size_t)(hn * 64 + rr) * 64) * 256;
#pragma unroll
  for (int p = 0; p < 2; ++p) {
    int c2 = cj + p * 4;
    us8 v = *reinterpret_cast<const us8*>(lds + dd * LDP + c2 * 8);
    *reinterpret_cast<us8*>(V + ob + (size_t)dd * 256 + jt * 64 + c2 * 8) = v;
  }
}

// Scores, split-K x4, GATHER-STAGED from qkvb (r5-proven, reg-staged, LDP pad).
// Spart[s][hn][i][j] = partial over rr in [s*16,(s+1)*16). grid 384.
__global__ __launch_bounds__(256) void k_gemm_scores(
    const unsigned short* __restrict__ qkvb, float* __restrict__ Spart)
{
  __shared__ unsigned short Asp[128 * LDP], Bsp[128 * LDP];
  int bx = blockIdx.x;
  int s = bx / 96, rblk = bx % 96;
  int hn = rblk >> 2, tt = rblk & 3, bm = tt >> 1, bn = tt & 1;
  int h = hn >> 1, nn = hn & 1;
  const int hq = h * 64;
  f32x4 acc[4][4]; ACC_ZERO(acc);

  const int tid = threadIdx.x, lane = tid & 63, wid = tid >> 6;
  const int wr = wid >> 1, wc = wid & 1, lr = lane & 15, kg = lane >> 4;
  const int srow = tid >> 3, sch = tid & 7;

  for (int t = 0; t < 16; ++t) {
    int rr = s * 16 + t;
    us8 av[4], bv[4];
#pragma unroll
    for (int c = 0; c < 4; ++c) {
      int row = c * 32 + srow;
      size_t ab = ((size_t)((rr * 256 + bm * 128 + row) * 2 + nn)) * 2304 + hq + sch * 8;
      size_t bb = ((size_t)((rr * 256 + bn * 128 + row) * 2 + nn)) * 2304 + 768 + hq + sch * 8;
      av[c] = *reinterpret_cast<const us8*>(qkvb + ab);
      bv[c] = *reinterpret_cast<const us8*>(qkvb + bb);
    }
    __syncthreads();
#pragma unroll
    for (int c = 0; c < 4; ++c) {
      int row = c * 32 + srow;
      *reinterpret_cast<us8*>(Asp + row * LDP + sch * 8) = av[c];
      *reinterpret_cast<us8*>(Bsp + row * LDP + sch * 8) = bv[c];
    }
    __syncthreads();
#pragma unroll
    for (int ks = 0; ks < 2; ++ks) {
      bf16x8 af[4], bfr[4];
#pragma unroll
      for (int mi = 0; mi < 4; ++mi)
        af[mi] = *reinterpret_cast<const bf16x8*>(Asp + (wr*64 + mi*16 + lr) * LDP + ks*32 + kg*8);
#pragma unroll
      for (int ni = 0; ni < 4; ++ni)
        bfr[ni] = *reinterpret_cast<const bf16x8*>(Bsp + (wc*64 + ni*16 + lr) * LDP + ks*32 + kg*8);
#pragma unroll
      for (int mi = 0; mi < 4; ++mi)
#pragma unroll
        for (int ni = 0; ni < 4; ++ni)
          acc[mi][ni] = __builtin_amdgcn_mfma_f32_16x16x32_bf16(af[mi], bfr[ni], acc[mi][ni], 0, 0, 0);
    }
  }

  float* Ss = Spart + ((size_t)s * 24 + hn) * 65536;
#pragma unroll
  for (int mi = 0; mi < 4; ++mi)
#pragma unroll
    for (int ni = 0; ni < 4; ++ni)
#pragma unroll
      for (int e = 0; e < 4; ++e) {
        int row = bm * 128 + wr * 64 + mi * 16 + kg * 4 + e;
        int col = bn * 128 + wc * 64 + ni * 16 + lr;
        Ss[(size_t)row * 256 + col] = acc[mi][ni][e];
      }
}

// Row softmax over j=256 with 4-way split-K reduction. grid 6144 (= hn*256+i rows).
__global__ __launch_bounds__(256) void k_softmax(const float* __restrict__ Sp,
                                                 unsigned short* __restrict__ P)
{
  __shared__ float red[8];
  size_t row = blockIdx.x;
  int t = threadIdx.x, wid = t >> 6, lane = t & 63;
  size_t idx = row * 256 + t;
  float v = Sp[idx] + Sp[idx + 1572864] + Sp[idx + 2 * 1572864] + Sp[idx + 3 * 1572864];
  float m = v;
#pragma unroll
  for (int o = 32; o; o >>= 1) m = fmaxf(m, __shfl_xor(m, o));
  if (lane == 0) red[wid] = m;
  __syncthreads();
  m = fmaxf(fmaxf(red[0], red[1]), fmaxf(red[2], red[3]));
  float e = __expf(v - m);
  float sm = e;
#pragma unroll
  for (int o = 32; o; o >>= 1) sm += __shfl_xor(sm, o);
  if (lane == 0) red[4 + wid] = sm;
  __syncthreads();
  sm = red[4] + red[5] + red[6] + red[7];
  P[row * 256 + t] = f2bf(e / sm);
}

// Context: per (h,n): C2[i][c=(rr,dd)] = sum_j P[i][j] V[c][j]; scatter to Cb[t][e].
// grid 24 * (2 x 32) = 1536, XCD-swizzled.
__global__ __launch_bounds__(256) void k_gemm_ctx(
    const unsigned short* __restrict__ P, const unsigned short* __restrict__ V,
    unsigned short* __restrict__ Cb)
{
  GEMM_LDS;
  int b0 = blockIdx.x;
  int bx = (b0 & 7) * 192 + (b0 >> 3);     // bijective (1536 = 8 * 192)
  int hn = bx / 64, tt = bx % 64, bm = tt >> 5, bn = tt & 31;
  f32x4 acc[4][4]; ACC_ZERO(acc);
  const unsigned short* Ag = P + (size_t)hn * 65536 + (size_t)bm * 128 * 256;
  const unsigned short* Bg = V + (size_t)hn * 4096 * 256 + (size_t)bn * 128 * 256;
  gemm_core(Ag, 256, Bg, 256, 256, As, Bs, acc);
  EPI_VARS;
  int nn = hn & 1;
  int h = hn >> 1;
#pragma unroll
  for (int mi = 0; mi < 4; ++mi)
#pragma unroll
    for (int ni = 0; ni < 4; ++ni) {
      int c = bn * 128 + wc * 64 + ni * 16 + lr;   // rr*64+dd
      int rr = c >> 6, dd = c & 63;
#pragma unroll
      for (int e = 0; e < 4; ++e) {
        int i = bm * 128 + wr * 64 + mi * 16 + kg * 4 + e;
        int tok = (rr * 256 + i) * 2 + nn;
        Cb[(size_t)tok * 768 + h * 64 + dd] = f2bf(acc[mi][ni][e]);
      }
    }
}

// Output projection: out[t][e] = C @ Wo + bo (fp32). grid 1536 (XCD-swizzled).
__global__ __launch_bounds__(256) void k_gemm_out(
    const unsigned short* __restrict__ Cb, const unsigned short* __restrict__ woT,
    const float* __restrict__ bo, float* __restrict__ out)
{
  GEMM_LDS;
  int b0 = blockIdx.x;
  int bx = (b0 & 7) * 192 + (b0 >> 3);     // bijective (1536 % 8 == 0)
  int bn = bx % 6, bm = bx / 6;
  f32x4 acc[4][4]; ACC_ZERO(acc);
  gemm_core(Cb + (size_t)bm * 128 * 768, 768, woT + (size_t)bn * 128 * 768, 768, 768, As, Bs, acc);
  EPI_VARS;
#pragma unroll
  for (int mi = 0; mi < 4; ++mi)
#pragma unroll
    for (int ni = 0; ni < 4; ++ni) {
      int col = bn * 128 + wc * 64 + ni * 16 + lr;
      float bias = bo[col];
#pragma unroll
      for (int e = 0; e < 4; ++e) {
        int row = bm * 128 + wr * 64 + mi * 16 + kg * 4 + e;
        out[(size_t)row * 768 + col] = acc[mi][ni][e] + bias;
      }
    }
}

// ======================================================================
extern "C" void kernel_launch(void* const* d_in, const int* in_sizes, int n_in,
                              void* d_out, int out_size, void* d_ws, size_t ws_size,
                              hipStream_t stream)
{
  const float* x  = (const float*)d_in[0];
  const float* Wq = (const float*)d_in[1];
  const float* bq = (const float*)d_in[2];
  const float* Wk = (const float*)d_in[3];
  const float* bk = (const float*)d_in[4];
  const float* Wv = (const float*)d_in[5];
  const float* bv = (const float*)d_in[6];
  const float* Wo = (const float*)d_in[7];
  const float* bo = (const float*)d_in[8];
  float* out = (float*)d_out;

  char* ws = (char*)d_ws;
  size_t off = 0;
  auto alloc = [&](size_t bytes) { void* p = ws + off; off += (bytes + 255) & ~(size_t)255; return p; };
  unsigned short* xb   = (unsigned short*)alloc(50331648);   // x bf16 [t][768]
  unsigned short* qkvb = (unsigned short*)alloc(150994944);  // [t][2304] bf16
  unsigned short* Vb   = (unsigned short*)alloc(50331648);   // V [hn][4096][256]
  unsigned short* Cb   = (unsigned short*)alloc(50331648);   // context [t][768] bf16
  unsigned short* wT   = (unsigned short*)alloc(3538944);    // [2304][768] bf16
  unsigned short* woT  = (unsigned short*)alloc(1179648);    // [768][768] bf16
  float*          bqkv = (float*)alloc(9216);
  if (off > ws_size) return;

  // Scores partials + probs live in d_out (28.3MB of 100.6MB); both are fully
  // consumed by k_gemm_ctx before k_gemm_out overwrites d_out with the result.
  float*          Sp = (float*)d_out;                                   // [4][hn][256][256] f32
  unsigned short* P  = (unsigned short*)((char*)d_out + 25165824);      // [hn][256][256] bf16

  k_cvt_x      <<<24576, 256, 0, stream>>>(x, xb);
  k_cvt_w      <<<9225,  256, 0, stream>>>(Wq, Wk, Wv, Wo, bq, bk, bv, wT, woT, bqkv);
  k_gemm_qkv   <<<4608,  256, 0, stream>>>(xb, wT, bqkv, qkvb);
  k_repack_v   <<<6144,  256, 0, stream>>>(qkvb, Vb);
  k_gemm_scores<<<384,   256, 0, stream>>>(qkvb, Sp);
  k_softmax    <<<6144,  256, 0, stream>>>(Sp, P);
  k_gemm_ctx   <<<1536,  256, 0, stream>>>(P, Vb, Cb);
  k_gemm_out   <<<1536,  256, 0, stream>>>(Cb, woT, bo, out);
}

// Round 10
// 366.462 us; speedup vs baseline: 1.0166x; 1.0166x over previous
//
#include <hip/hip_runtime.h>
#include <stdint.h>

// ---- types ----
typedef __attribute__((ext_vector_type(8))) short bf16x8;     // 8 x bf16 = 4 VGPR
typedef __attribute__((ext_vector_type(4))) float f32x4;
typedef __attribute__((ext_vector_type(4))) unsigned short us4;
typedef __attribute__((ext_vector_type(8))) unsigned short us8;

// fp32 -> bf16 round-to-nearest-even
static __device__ __forceinline__ unsigned short f2bf(float f) {
  union { float f; unsigned u; } c; c.f = f;
  unsigned r = c.u + 0x7fffu + ((c.u >> 16) & 1u);
  return (unsigned short)(r >> 16);
}

// async global->LDS, 16B per lane. LDS dest is WAVE-UNIFORM base; HW writes
// lane l at base + l*16. Global src is per-lane.
static __device__ __forceinline__ void gl_lds16(const unsigned short* g, unsigned short* l) {
  __builtin_amdgcn_global_load_lds(
      (const __attribute__((address_space(1))) unsigned int*)g,
      (__attribute__((address_space(3))) unsigned int*)l, 16, 0, 0);
}

// Problem constants: x (r=64, i=256, n=2, E=768), h=12, d=64.
// tokens T = 32768 in (r,i,n) order (n fastest); scores K-dim = r*d = 4096; hn = 24.
#define LDP 80   // padded LDS row for the reg-staged kernels (conflict-free, measured 0)

// ======================================================================
// 256x256 8-wave phase-interleaved GEMM core (T2+T3+T4+T5).
// 512 thr = 8 waves (2M x 4N); per-wave C = 128x64 = 8x4 frags of 16x16x32.
// BK=64; LDS = 2 dbuf x (A[256][64] + B[256][64]) bf16 = 128 KiB.
// Per K-tile: 4 phases; phase q = {4 ds_read_b128 (A-frags) || 1 stage-chunk
// (2 global_load_lds) || 16 MFMA in setprio(1)}. Sync: counted vmcnt(2) +
// barrier at tile top (all waves' tile-t loads visible), barrier at tile end
// (buffer free). Race audit: stage of t+1 issues only after end-barrier of
// t-1; per-wave vmcnt + barrier = global visibility (r8-proven contract).
// XOR swizzle (rule #21): LDS unit u of row holds source chunk u ^ (row&7);
// fragment read applies the same XOR. Conflicts measured 0 at this math.
// ======================================================================
#define QT 16384   // elems per operand K-tile (256*64)

__device__ __forceinline__ void gemm256_core(
    const unsigned short* __restrict__ Ag, int lda,
    const unsigned short* __restrict__ Bg, int ldb,
    int K, unsigned short* As, unsigned short* Bs, f32x4 acc[8][4])
{
  const int tid  = threadIdx.x;
  const int lane = tid & 63;
  const int wid  = tid >> 6;            // 0..7
  const int wr = wid >> 2, wc = wid & 3;
  const int lr = lane & 15, kg = lane >> 4;
  const int l7 = lane & 7;
  const int srow = tid >> 3;            // 0..63 (chunk-local row)
  const int sch  = (tid & 7) ^ (srow & 7);   // inverse-swizzled source chunk

  auto STG = [&](int c, int kt, int bufo) {
    int row = c * 64 + srow;
    gl_lds16(Ag + row * lda + kt + sch * 8, As + bufo + ((c * 512 + wid * 64) << 3));
    gl_lds16(Bg + row * ldb + kt + sch * 8, Bs + bufo + ((c * 512 + wid * 64) << 3));
  };

  const int nt = K >> 6;
  STG(0, 0, 0); STG(1, 0, 0); STG(2, 0, 0); STG(3, 0, 0);   // prologue: tile 0
  int cur = 0;
  for (int t = 0; t < nt; ++t) {
    const bool last = (t == nt - 1);
    const int kt1 = (t + 1) << 6;
    const int cb = cur * QT, nb = (cur ^ 1) * QT;
    if (!last) STG(0, kt1, nb);                       // chunk 0 of t+1 in flight
    if (last) asm volatile("s_waitcnt vmcnt(0)" ::: "memory");
    else      asm volatile("s_waitcnt vmcnt(2)" ::: "memory");   // tile t landed
    __builtin_amdgcn_s_barrier();
    // B fragments for the whole K-tile (shared by all 4 phases)
    bf16x8 bf[4][2];
#pragma unroll
    for (int ni = 0; ni < 4; ++ni)
#pragma unroll
      for (int ks = 0; ks < 2; ++ks)
        bf[ni][ks] = *reinterpret_cast<const bf16x8*>(
            Bs + cb + (wc*64 + ni*16 + lr) * 64 + (((ks*4 + kg) ^ l7) << 3));
#pragma unroll
    for (int q = 0; q < 4; ++q) {                     // 4 phases = C-quadrants
      bf16x8 af[2][2];
#pragma unroll
      for (int m2 = 0; m2 < 2; ++m2)
#pragma unroll
        for (int ks = 0; ks < 2; ++ks)
          af[m2][ks] = *reinterpret_cast<const bf16x8*>(
              As + cb + (wr*128 + (q*2 + m2)*16 + lr) * 64 + (((ks*4 + kg) ^ l7) << 3));
      if (!last && q < 3) STG(q + 1, kt1, nb);        // interleave stage w/ MFMA
      __builtin_amdgcn_s_setprio(1);
#pragma unroll
      for (int ks = 0; ks < 2; ++ks)
#pragma unroll
        for (int m2 = 0; m2 < 2; ++m2)
#pragma unroll
          for (int ni = 0; ni < 4; ++ni)
            acc[q*2 + m2][ni] = __builtin_amdgcn_mfma_f32_16x16x32_bf16(
                af[m2][ks], bf[ni][ks], acc[q*2 + m2][ni], 0, 0, 0);
      __builtin_amdgcn_s_setprio(0);
    }
    __builtin_amdgcn_s_barrier();                     // all reads of buf done
    cur ^= 1;
  }
}

// ======================================================================
// r8-proven 128x128 counted-vmcnt dbuf core (kept for ctx).
// ======================================================================
__device__ __forceinline__ void stage8(
    const unsigned short* __restrict__ Ag, int lda,
    const unsigned short* __restrict__ Bg, int ldb, int kt,
    unsigned short* As, unsigned short* Bs, int tid, int wid)
{
#pragma unroll
  for (int c = 0; c < 4; ++c) {
    int chunk = c * 256 + tid;
    int row = chunk >> 3, u = chunk & 7;
    int ch = u ^ (row & 7);
    gl_lds16(Ag + row * lda + kt + ch * 8, As + ((c * 256 + wid * 64) << 3));
    gl_lds16(Bg + row * ldb + kt + ch * 8, Bs + ((c * 256 + wid * 64) << 3));
  }
}

__device__ __forceinline__ void compute64(
    const unsigned short* As, const unsigned short* Bs, f32x4 acc[4][4],
    int wr, int wc, int lr, int kg, int l7)
{
#pragma unroll
  for (int ks = 0; ks < 2; ++ks) {
    bf16x8 af[4], bfr[4];
    int u = (ks * 4 + kg) ^ l7;
#pragma unroll
    for (int mi = 0; mi < 4; ++mi)
      af[mi] = *reinterpret_cast<const bf16x8*>(As + (wr*64 + mi*16 + lr) * 64 + u * 8);
#pragma unroll
    for (int ni = 0; ni < 4; ++ni)
      bfr[ni] = *reinterpret_cast<const bf16x8*>(Bs + (wc*64 + ni*16 + lr) * 64 + u * 8);
#pragma unroll
    for (int mi = 0; mi < 4; ++mi)
#pragma unroll
      for (int ni = 0; ni < 4; ++ni)
        acc[mi][ni] = __builtin_amdgcn_mfma_f32_16x16x32_bf16(af[mi], bfr[ni], acc[mi][ni], 0, 0, 0);
  }
}

__device__ __forceinline__ void gemm_core(
    const unsigned short* __restrict__ Ag, int lda,
    const unsigned short* __restrict__ Bg, int ldb,
    int K, unsigned short* As, unsigned short* Bs, f32x4 acc[4][4])
{
  const int tid  = threadIdx.x;
  const int lane = tid & 63;
  const int wid  = tid >> 6;
  const int wr = wid >> 1, wc = wid & 1;
  const int lr = lane & 15, kg = lane >> 4;
  const int l7 = lane & 7;

  const int nt = K >> 6;
  stage8(Ag, lda, Bg, ldb, 0, As, Bs, tid, wid);
  int cur = 0;
  for (int t = 0; t < nt - 1; ++t) {
    stage8(Ag, lda, Bg, ldb, (t + 1) << 6,
           As + (cur ^ 1) * 8192, Bs + (cur ^ 1) * 8192, tid, wid);
    asm volatile("s_waitcnt vmcnt(8)" ::: "memory");
    __builtin_amdgcn_s_barrier();
    compute64(As + cur * 8192, Bs + cur * 8192, acc, wr, wc, lr, kg, l7);
    __builtin_amdgcn_s_barrier();
    cur ^= 1;
  }
  asm volatile("s_waitcnt vmcnt(0)" ::: "memory");
  __builtin_amdgcn_s_barrier();
  compute64(As + cur * 8192, Bs + cur * 8192, acc, wr, wc, lr, kg, l7);
}

#define ACC_ZERO(acc) do { \
  f32x4 z = {0.f, 0.f, 0.f, 0.f}; \
  for (int a_ = 0; a_ < 4; ++a_) for (int b_ = 0; b_ < 4; ++b_) acc[a_][b_] = z; } while (0)

#define ACC_ZERO8(acc) do { \
  f32x4 z = {0.f, 0.f, 0.f, 0.f}; \
  for (int a_ = 0; a_ < 8; ++a_) for (int b_ = 0; b_ < 4; ++b_) acc[a_][b_] = z; } while (0)

#define EPI_VARS \
  int tid = threadIdx.x, lane = tid & 63, wid = tid >> 6; \
  int wr = wid >> 1, wc = wid & 1, lr = lane & 15, kg = lane >> 4; (void)wr; (void)wc;

#define GEMM_LDS \
  __shared__ unsigned short As[2 * 128 * 64], Bs[2 * 128 * 64];

// ======================================================================
// Kernels
// ======================================================================

// x fp32 -> bf16, 4 elems/thread. grid 24576x256 covers 25165824 exactly.
__global__ __launch_bounds__(256) void k_cvt_x(const float* __restrict__ x,
                                               unsigned short* __restrict__ xb) {
  int i = blockIdx.x * 256 + threadIdx.x;
  f32x4 f = reinterpret_cast<const f32x4*>(x)[i];
  us4 o = { f2bf(f[0]), f2bf(f[1]), f2bf(f[2]), f2bf(f[3]) };
  reinterpret_cast<us4*>(xb)[i] = o;
}

// Transposed bf16 weights wT[col][k] (q-part pre-scaled by 1/64), woT[col][k],
// fused bias bqkv (q-part scaled). grid 9225x256 = 2361600 exactly.
__global__ __launch_bounds__(256) void k_cvt_w(
    const float* __restrict__ Wq, const float* __restrict__ Wk, const float* __restrict__ Wv,
    const float* __restrict__ Wo, const float* __restrict__ bq, const float* __restrict__ bk,
    const float* __restrict__ bv, unsigned short* __restrict__ wT,
    unsigned short* __restrict__ woT, float* __restrict__ bqkv)
{
  const float qs = 1.0f / 64.0f;  // d^-0.5 / sqrt(r) = (1/8)/8
  int o = blockIdx.x * 256 + threadIdx.x;
  if (o < 2304 * 768) {
    int col = o / 768, k = o % 768;
    float v;
    if (col < 768)       v = Wq[k * 768 + col] * qs;
    else if (col < 1536) v = Wk[k * 768 + col - 768];
    else                 v = Wv[k * 768 + col - 1536];
    wT[o] = f2bf(v);
  } else if (o < 2304 * 768 + 768 * 768) {
    int o2 = o - 2304 * 768;
    int col = o2 / 768, k = o2 % 768;
    woT[o2] = f2bf(Wo[k * 768 + col]);
  } else {
    int o3 = o - (2304 * 768 + 768 * 768);
    float v = (o3 < 768) ? bq[o3] * qs : (o3 < 1536 ? bk[o3 - 768] : bv[o3 - 1536]);
    bqkv[o3] = v;
  }
}

// QKV projection, 256x256 8-wave core: qkvb[t][0..2303] = bf16(x@[Wq|Wk|Wv]+b).
// grid 1152 = 128 bm x 9 bn (bn-fast: consecutive blocks share the xb tile).
__global__ __launch_bounds__(512, 2) void k_gemm_qkv(
    const unsigned short* __restrict__ xb, const unsigned short* __restrict__ wT,
    const float* __restrict__ bqkv, unsigned short* __restrict__ qkvb)
{
  __shared__ unsigned short As[2 * QT], Bs[2 * QT];   // 128 KiB
  int bx = blockIdx.x, bn = bx % 9, bm = bx / 9;
  f32x4 acc[8][4]; ACC_ZERO8(acc);
  gemm256_core(xb + (size_t)bm * 256 * 768, 768, wT + (size_t)bn * 256 * 768, 768,
               768, As, Bs, acc);
  const int lane = threadIdx.x & 63, wid = threadIdx.x >> 6;
  const int wr = wid >> 2, wc = wid & 3, lr = lane & 15, kg = lane >> 4;
#pragma unroll
  for (int mi = 0; mi < 8; ++mi)
#pragma unroll
    for (int ni = 0; ni < 4; ++ni) {
      int col = bn * 256 + wc * 64 + ni * 16 + lr;
      float bias = bqkv[col];
#pragma unroll
      for (int e = 0; e < 4; ++e) {
        int row = bm * 256 + wr * 128 + mi * 16 + kg * 4 + e;   // token
        qkvb[(size_t)row * 2304 + col] = f2bf(acc[mi][ni][e] + bias);
      }
    }
}

// Repack v -> V[h][n][rr*64+dd][j=i] (j-contiguous) via LDS 64x64 transpose.
// Reads qkvb directly. grid 24*64*4 = 6144 blocks.
__global__ __launch_bounds__(256) void k_repack_v(
    const unsigned short* __restrict__ qkvb, unsigned short* __restrict__ V)
{
  __shared__ unsigned short lds[64 * LDP];
  int bx = blockIdx.x;
  int jt = bx & 3, rr = (bx >> 2) & 63, hn = bx >> 8;
  int h = hn >> 1, nn = hn & 1;
  int t = threadIdx.x;
  int j = t >> 3, ch = t & 7;
#pragma unroll
  for (int p = 0; p < 2; ++p) {
    int jj = p * 32 + j;
    us8 v = *reinterpret_cast<const us8*>(
        qkvb + ((size_t)((rr * 256 + jt * 64 + jj) * 2 + nn)) * 2304 + 1536 + h * 64 + ch * 8);
#pragma unroll
    for (int e = 0; e < 8; ++e) lds[(ch * 8 + e) * LDP + jj] = v[e];
  }
  __syncthreads();
  int dd = t >> 2, cj = t & 3;
  size_t ob = ((size_t)(hn * 64 + rr) * 64) * 256;
#pragma unroll
  for (int p = 0; p < 2; ++p) {
    int c2 = cj + p * 4;
    us8 v = *reinterpret_cast<const us8*>(lds + dd * LDP + c2 * 8);
    *reinterpret_cast<us8*>(V + ob + (size_t)dd * 256 + jt * 64 + c2 * 8) = v;
  }
}

// Scores, split-K x4, GATHER-STAGED from qkvb (r5-proven, reg-staged, LDP pad).
// Spart[s][hn][i][j] = partial over rr in [s*16,(s+1)*16). grid 384.
__global__ __launch_bounds__(256) void k_gemm_scores(
    const unsigned short* __restrict__ qkvb, float* __restrict__ Spart)
{
  __shared__ unsigned short Asp[128 * LDP], Bsp[128 * LDP];
  int bx = blockIdx.x;
  int s = bx / 96, rblk = bx % 96;
  int hn = rblk >> 2, tt = rblk & 3, bm = tt >> 1, bn = tt & 1;
  int h = hn >> 1, nn = hn & 1;
  const int hq = h * 64;
  f32x4 acc[4][4]; ACC_ZERO(acc);

  const int tid = threadIdx.x, lane = tid & 63, wid = tid >> 6;
  const int wr = wid >> 1, wc = wid & 1, lr = lane & 15, kg = lane >> 4;
  const int srow = tid >> 3, sch = tid & 7;

  for (int t = 0; t < 16; ++t) {
    int rr = s * 16 + t;
    us8 av[4], bv[4];
#pragma unroll
    for (int c = 0; c < 4; ++c) {
      int row = c * 32 + srow;
      size_t ab = ((size_t)((rr * 256 + bm * 128 + row) * 2 + nn)) * 2304 + hq + sch * 8;
      size_t bb = ((size_t)((rr * 256 + bn * 128 + row) * 2 + nn)) * 2304 + 768 + hq + sch * 8;
      av[c] = *reinterpret_cast<const us8*>(qkvb + ab);
      bv[c] = *reinterpret_cast<const us8*>(qkvb + bb);
    }
    __syncthreads();
#pragma unroll
    for (int c = 0; c < 4; ++c) {
      int row = c * 32 + srow;
      *reinterpret_cast<us8*>(Asp + row * LDP + sch * 8) = av[c];
      *reinterpret_cast<us8*>(Bsp + row * LDP + sch * 8) = bv[c];
    }
    __syncthreads();
#pragma unroll
    for (int ks = 0; ks < 2; ++ks) {
      bf16x8 af[4], bfr[4];
#pragma unroll
      for (int mi = 0; mi < 4; ++mi)
        af[mi] = *reinterpret_cast<const bf16x8*>(Asp + (wr*64 + mi*16 + lr) * LDP + ks*32 + kg*8);
#pragma unroll
      for (int ni = 0; ni < 4; ++ni)
        bfr[ni] = *reinterpret_cast<const bf16x8*>(Bsp + (wc*64 + ni*16 + lr) * LDP + ks*32 + kg*8);
#pragma unroll
      for (int mi = 0; mi < 4; ++mi)
#pragma unroll
        for (int ni = 0; ni < 4; ++ni)
          acc[mi][ni] = __builtin_amdgcn_mfma_f32_16x16x32_bf16(af[mi], bfr[ni], acc[mi][ni], 0, 0, 0);
    }
  }

  float* Ss = Spart + ((size_t)s * 24 + hn) * 65536;
#pragma unroll
  for (int mi = 0; mi < 4; ++mi)
#pragma unroll
    for (int ni = 0; ni < 4; ++ni)
#pragma unroll
      for (int e = 0; e < 4; ++e) {
        int row = bm * 128 + wr * 64 + mi * 16 + kg * 4 + e;
        int col = bn * 128 + wc * 64 + ni * 16 + lr;
        Ss[(size_t)row * 256 + col] = acc[mi][ni][e];
      }
}

// Row softmax over j=256 with 4-way split-K reduction. grid 6144 (= hn*256+i rows).
__global__ __launch_bounds__(256) void k_softmax(const float* __restrict__ Sp,
                                                 unsigned short* __restrict__ P)
{
  __shared__ float red[8];
  size_t row = blockIdx.x;
  int t = threadIdx.x, wid = t >> 6, lane = t & 63;
  size_t idx = row * 256 + t;
  float v = Sp[idx] + Sp[idx + 1572864] + Sp[idx + 2 * 1572864] + Sp[idx + 3 * 1572864];
  float m = v;
#pragma unroll
  for (int o = 32; o; o >>= 1) m = fmaxf(m, __shfl_xor(m, o));
  if (lane == 0) red[wid] = m;
  __syncthreads();
  m = fmaxf(fmaxf(red[0], red[1]), fmaxf(red[2], red[3]));
  float e = __expf(v - m);
  float sm = e;
#pragma unroll
  for (int o = 32; o; o >>= 1) sm += __shfl_xor(sm, o);
  if (lane == 0) red[4 + wid] = sm;
  __syncthreads();
  sm = red[4] + red[5] + red[6] + red[7];
  P[row * 256 + t] = f2bf(e / sm);
}

// Context: per (h,n): C2[i][c=(rr,dd)] = sum_j P[i][j] V[c][j]; scatter to Cb[t][e].
// grid 24 * (2 x 32) = 1536 (no swizzle — r9's ctx swizzle regressed).
__global__ __launch_bounds__(256) void k_gemm_ctx(
    const unsigned short* __restrict__ P, const unsigned short* __restrict__ V,
    unsigned short* __restrict__ Cb)
{
  GEMM_LDS;
  int bx = blockIdx.x;
  int hn = bx / 64, tt = bx % 64, bm = tt >> 5, bn = tt & 31;
  f32x4 acc[4][4]; ACC_ZERO(acc);
  const unsigned short* Ag = P + (size_t)hn * 65536 + (size_t)bm * 128 * 256;
  const unsigned short* Bg = V + (size_t)hn * 4096 * 256 + (size_t)bn * 128 * 256;
  gemm_core(Ag, 256, Bg, 256, 256, As, Bs, acc);
  EPI_VARS;
  int nn = hn & 1;
  int h = hn >> 1;
#pragma unroll
  for (int mi = 0; mi < 4; ++mi)
#pragma unroll
    for (int ni = 0; ni < 4; ++ni) {
      int c = bn * 128 + wc * 64 + ni * 16 + lr;   // rr*64+dd
      int rr = c >> 6, dd = c & 63;
#pragma unroll
      for (int e = 0; e < 4; ++e) {
        int i = bm * 128 + wr * 64 + mi * 16 + kg * 4 + e;
        int tok = (rr * 256 + i) * 2 + nn;
        Cb[(size_t)tok * 768 + h * 64 + dd] = f2bf(acc[mi][ni][e]);
      }
    }
}

// Output projection, 256x256 8-wave core: out[t][e] = C @ Wo + bo (fp32).
// grid 384 = 128 bm x 3 bn (bn-fast).
__global__ __launch_bounds__(512, 2) void k_gemm_out(
    const unsigned short* __restrict__ Cb, const unsigned short* __restrict__ woT,
    const float* __restrict__ bo, float* __restrict__ out)
{
  __shared__ unsigned short As[2 * QT], Bs[2 * QT];   // 128 KiB
  int bx = blockIdx.x, bn = bx % 3, bm = bx / 3;
  f32x4 acc[8][4]; ACC_ZERO8(acc);
  gemm256_core(Cb + (size_t)bm * 256 * 768, 768, woT + (size_t)bn * 256 * 768, 768,
               768, As, Bs, acc);
  const int lane = threadIdx.x & 63, wid = threadIdx.x >> 6;
  const int wr = wid >> 2, wc = wid & 3, lr = lane & 15, kg = lane >> 4;
#pragma unroll
  for (int mi = 0; mi < 8; ++mi)
#pragma unroll
    for (int ni = 0; ni < 4; ++ni) {
      int col = bn * 256 + wc * 64 + ni * 16 + lr;
      float bias = bo[col];
#pragma unroll
      for (int e = 0; e < 4; ++e) {
        int row = bm * 256 + wr * 128 + mi * 16 + kg * 4 + e;
        out[(size_t)row * 768 + col] = acc[mi][ni][e] + bias;
      }
    }
}

// ======================================================================
extern "C" void kernel_launch(void* const* d_in, const int* in_sizes, int n_in,
                              void* d_out, int out_size, void* d_ws, size_t ws_size,
                              hipStream_t stream)
{
  const float* x  = (const float*)d_in[0];
  const float* Wq = (const float*)d_in[1];
  const float* bq = (const float*)d_in[2];
  const float* Wk = (const float*)d_in[3];
  const float* bk = (const float*)d_in[4];
  const float* Wv = (const float*)d_in[5];
  const float* bv = (const float*)d_in[6];
  const float* Wo = (const float*)d_in[7];
  const float* bo = (const float*)d_in[8];
  float* out = (float*)d_out;

  char* ws = (char*)d_ws;
  size_t off = 0;
  auto alloc = [&](size_t bytes) { void* p = ws + off; off += (bytes + 255) & ~(size_t)255; return p; };
  unsigned short* xb   = (unsigned short*)alloc(50331648);   // x bf16 [t][768]
  unsigned short* qkvb = (unsigned short*)alloc(150994944);  // [t][2304] bf16
  unsigned short* Vb   = (unsigned short*)alloc(50331648);   // V [hn][4096][256]
  unsigned short* Cb   = (unsigned short*)alloc(50331648);   // context [t][768] bf16
  unsigned short* wT   = (unsigned short*)alloc(3538944);    // [2304][768] bf16
  unsigned short* woT  = (unsigned short*)alloc(1179648);    // [768][768] bf16
  float*          bqkv = (float*)alloc(9216);
  if (off > ws_size) return;

  // Scores partials + probs live in d_out (28.3MB of 100.6MB); both are fully
  // consumed by k_gemm_ctx before k_gemm_out overwrites d_out with the result.
  float*          Sp = (float*)d_out;                                   // [4][hn][256][256] f32
  unsigned short* P  = (unsigned short*)((char*)d_out + 25165824);      // [hn][256][256] bf16

  k_cvt_x      <<<24576, 256, 0, stream>>>(x, xb);
  k_cvt_w      <<<9225,  256, 0, stream>>>(Wq, Wk, Wv, Wo, bq, bk, bv, wT, woT, bqkv);
  k_gemm_qkv   <<<1152,  512, 0, stream>>>(xb, wT, bqkv, qkvb);
  k_repack_v   <<<6144,  256, 0, stream>>>(qkvb, Vb);
  k_gemm_scores<<<384,   256, 0, stream>>>(qkvb, Sp);
  k_softmax    <<<6144,  256, 0, stream>>>(Sp, P);
  k_gemm_ctx   <<<1536,  256, 0, stream>>>(P, Vb, Cb);
  k_gemm_out   <<<384,   512, 0, stream>>>(Cb, woT, bo, out);
}

// Round 11
// 336.287 us; speedup vs baseline: 1.1078x; 1.0897x over previous
//
#include <hip/hip_runtime.h>
#include <stdint.h>

// ---- types ----
typedef __attribute__((ext_vector_type(8))) short bf16x8;     // 8 x bf16 = 4 VGPR
typedef __attribute__((ext_vector_type(4))) float f32x4;
typedef __attribute__((ext_vector_type(4))) unsigned short us4;
typedef __attribute__((ext_vector_type(8))) unsigned short us8;

// fp32 -> bf16 round-to-nearest-even
static __device__ __forceinline__ unsigned short f2bf(float f) {
  union { float f; unsigned u; } c; c.f = f;
  unsigned r = c.u + 0x7fffu + ((c.u >> 16) & 1u);
  return (unsigned short)(r >> 16);
}

// async global->LDS, 16B per lane. LDS dest is WAVE-UNIFORM base; HW writes
// lane l at base + l*16. Global src is per-lane.
static __device__ __forceinline__ void gl_lds16(const unsigned short* g, unsigned short* l) {
  __builtin_amdgcn_global_load_lds(
      (const __attribute__((address_space(1))) unsigned int*)g,
      (__attribute__((address_space(3))) unsigned int*)l, 16, 0, 0);
}

// Problem constants: x (r=64, i=256, n=2, E=768), h=12, d=64.
// tokens T = 32768 in (r,i,n) order (n fastest); scores K-dim = r*d = 4096; hn = 24.
#define LDP 80   // padded LDS row for the reg-staged kernels (conflict-free, measured 0)
#define QT 16384 // elems per operand K-tile at 256-tile (256*64)

// ======================================================================
// 256x256 8-wave phase-interleaved core (r10-proven on qkv, 158us/737TF).
// ======================================================================
__device__ __forceinline__ void gemm256_core(
    const unsigned short* __restrict__ Ag, int lda,
    const unsigned short* __restrict__ Bg, int ldb,
    int K, unsigned short* As, unsigned short* Bs, f32x4 acc[8][4])
{
  const int tid  = threadIdx.x;
  const int lane = tid & 63;
  const int wid  = tid >> 6;            // 0..7
  const int wr = wid >> 2, wc = wid & 3;
  const int lr = lane & 15, kg = lane >> 4;
  const int l7 = lane & 7;
  const int srow = tid >> 3;            // 0..63 (chunk-local row)
  const int sch  = (tid & 7) ^ (srow & 7);   // inverse-swizzled source chunk

  auto STG = [&](int c, int kt, int bufo) {
    int row = c * 64 + srow;
    gl_lds16(Ag + row * lda + kt + sch * 8, As + bufo + ((c * 512 + wid * 64) << 3));
    gl_lds16(Bg + row * ldb + kt + sch * 8, Bs + bufo + ((c * 512 + wid * 64) << 3));
  };

  const int nt = K >> 6;
  STG(0, 0, 0); STG(1, 0, 0); STG(2, 0, 0); STG(3, 0, 0);   // prologue: tile 0
  int cur = 0;
  for (int t = 0; t < nt; ++t) {
    const bool last = (t == nt - 1);
    const int kt1 = (t + 1) << 6;
    const int cb = cur * QT, nb = (cur ^ 1) * QT;
    if (!last) STG(0, kt1, nb);                       // chunk 0 of t+1 in flight
    if (last) asm volatile("s_waitcnt vmcnt(0)" ::: "memory");
    else      asm volatile("s_waitcnt vmcnt(2)" ::: "memory");   // tile t landed
    __builtin_amdgcn_s_barrier();
    bf16x8 bf[4][2];
#pragma unroll
    for (int ni = 0; ni < 4; ++ni)
#pragma unroll
      for (int ks = 0; ks < 2; ++ks)
        bf[ni][ks] = *reinterpret_cast<const bf16x8*>(
            Bs + cb + (wc*64 + ni*16 + lr) * 64 + (((ks*4 + kg) ^ l7) << 3));
#pragma unroll
    for (int q = 0; q < 4; ++q) {                     // 4 phases = C-quadrants
      bf16x8 af[2][2];
#pragma unroll
      for (int m2 = 0; m2 < 2; ++m2)
#pragma unroll
        for (int ks = 0; ks < 2; ++ks)
          af[m2][ks] = *reinterpret_cast<const bf16x8*>(
              As + cb + (wr*128 + (q*2 + m2)*16 + lr) * 64 + (((ks*4 + kg) ^ l7) << 3));
      if (!last && q < 3) STG(q + 1, kt1, nb);        // interleave stage w/ MFMA
      __builtin_amdgcn_s_setprio(1);
#pragma unroll
      for (int ks = 0; ks < 2; ++ks)
#pragma unroll
        for (int m2 = 0; m2 < 2; ++m2)
#pragma unroll
          for (int ni = 0; ni < 4; ++ni)
            acc[q*2 + m2][ni] = __builtin_amdgcn_mfma_f32_16x16x32_bf16(
                af[m2][ks], bf[ni][ks], acc[q*2 + m2][ni], 0, 0, 0);
      __builtin_amdgcn_s_setprio(0);
    }
    __builtin_amdgcn_s_barrier();                     // all reads of buf done
    cur ^= 1;
  }
}

// ======================================================================
// r8-proven 128x128 counted-vmcnt dbuf core (ctx, out).
// ======================================================================
__device__ __forceinline__ void stage8(
    const unsigned short* __restrict__ Ag, int lda,
    const unsigned short* __restrict__ Bg, int ldb, int kt,
    unsigned short* As, unsigned short* Bs, int tid, int wid)
{
#pragma unroll
  for (int c = 0; c < 4; ++c) {
    int chunk = c * 256 + tid;
    int row = chunk >> 3, u = chunk & 7;
    int ch = u ^ (row & 7);
    gl_lds16(Ag + row * lda + kt + ch * 8, As + ((c * 256 + wid * 64) << 3));
    gl_lds16(Bg + row * ldb + kt + ch * 8, Bs + ((c * 256 + wid * 64) << 3));
  }
}

__device__ __forceinline__ void compute64(
    const unsigned short* As, const unsigned short* Bs, f32x4 acc[4][4],
    int wr, int wc, int lr, int kg, int l7)
{
#pragma unroll
  for (int ks = 0; ks < 2; ++ks) {
    bf16x8 af[4], bfr[4];
    int u = (ks * 4 + kg) ^ l7;
#pragma unroll
    for (int mi = 0; mi < 4; ++mi)
      af[mi] = *reinterpret_cast<const bf16x8*>(As + (wr*64 + mi*16 + lr) * 64 + u * 8);
#pragma unroll
    for (int ni = 0; ni < 4; ++ni)
      bfr[ni] = *reinterpret_cast<const bf16x8*>(Bs + (wc*64 + ni*16 + lr) * 64 + u * 8);
#pragma unroll
    for (int mi = 0; mi < 4; ++mi)
#pragma unroll
      for (int ni = 0; ni < 4; ++ni)
        acc[mi][ni] = __builtin_amdgcn_mfma_f32_16x16x32_bf16(af[mi], bfr[ni], acc[mi][ni], 0, 0, 0);
  }
}

__device__ __forceinline__ void gemm_core(
    const unsigned short* __restrict__ Ag, int lda,
    const unsigned short* __restrict__ Bg, int ldb,
    int K, unsigned short* As, unsigned short* Bs, f32x4 acc[4][4])
{
  const int tid  = threadIdx.x;
  const int lane = tid & 63;
  const int wid  = tid >> 6;
  const int wr = wid >> 1, wc = wid & 1;
  const int lr = lane & 15, kg = lane >> 4;
  const int l7 = lane & 7;

  const int nt = K >> 6;
  stage8(Ag, lda, Bg, ldb, 0, As, Bs, tid, wid);
  int cur = 0;
  for (int t = 0; t < nt - 1; ++t) {
    stage8(Ag, lda, Bg, ldb, (t + 1) << 6,
           As + (cur ^ 1) * 8192, Bs + (cur ^ 1) * 8192, tid, wid);
    asm volatile("s_waitcnt vmcnt(8)" ::: "memory");
    __builtin_amdgcn_s_barrier();
    compute64(As + cur * 8192, Bs + cur * 8192, acc, wr, wc, lr, kg, l7);
    __builtin_amdgcn_s_barrier();
    cur ^= 1;
  }
  asm volatile("s_waitcnt vmcnt(0)" ::: "memory");
  __builtin_amdgcn_s_barrier();
  compute64(As + cur * 8192, Bs + cur * 8192, acc, wr, wc, lr, kg, l7);
}

#define ACC_ZERO(acc) do { \
  f32x4 z = {0.f, 0.f, 0.f, 0.f}; \
  for (int a_ = 0; a_ < 4; ++a_) for (int b_ = 0; b_ < 4; ++b_) acc[a_][b_] = z; } while (0)

#define ACC_ZERO8(acc) do { \
  f32x4 z = {0.f, 0.f, 0.f, 0.f}; \
  for (int a_ = 0; a_ < 8; ++a_) for (int b_ = 0; b_ < 4; ++b_) acc[a_][b_] = z; } while (0)

#define EPI_VARS \
  int tid = threadIdx.x, lane = tid & 63, wid = tid >> 6; \
  int wr = wid >> 1, wc = wid & 1, lr = lane & 15, kg = lane >> 4; (void)wr; (void)wc;

#define GEMM_LDS \
  __shared__ unsigned short As[2 * 128 * 64], Bs[2 * 128 * 64];

// ======================================================================
// Kernels
// ======================================================================

// MERGED cvt_x + cvt_w (independent, disjoint outputs). grid 24576+9225=33801.
__global__ __launch_bounds__(256) void k_cvt_xw(
    const float* __restrict__ x, unsigned short* __restrict__ xb,
    const float* __restrict__ Wq, const float* __restrict__ Wk, const float* __restrict__ Wv,
    const float* __restrict__ Wo, const float* __restrict__ bq, const float* __restrict__ bk,
    const float* __restrict__ bv, unsigned short* __restrict__ wT,
    unsigned short* __restrict__ woT, float* __restrict__ bqkv)
{
  int b = blockIdx.x;
  if (b < 24576) {
    int i = b * 256 + threadIdx.x;
    f32x4 f = reinterpret_cast<const f32x4*>(x)[i];
    us4 o = { f2bf(f[0]), f2bf(f[1]), f2bf(f[2]), f2bf(f[3]) };
    reinterpret_cast<us4*>(xb)[i] = o;
    return;
  }
  const float qs = 1.0f / 64.0f;  // d^-0.5 / sqrt(r) = (1/8)/8
  int o = (b - 24576) * 256 + threadIdx.x;
  if (o < 2304 * 768) {
    int col = o / 768, k = o % 768;
    float v;
    if (col < 768)       v = Wq[k * 768 + col] * qs;
    else if (col < 1536) v = Wk[k * 768 + col - 768];
    else                 v = Wv[k * 768 + col - 1536];
    wT[o] = f2bf(v);
  } else if (o < 2304 * 768 + 768 * 768) {
    int o2 = o - 2304 * 768;
    int col = o2 / 768, k = o2 % 768;
    woT[o2] = f2bf(Wo[k * 768 + col]);
  } else {
    int o3 = o - (2304 * 768 + 768 * 768);
    float v = (o3 < 768) ? bq[o3] * qs : (o3 < 1536 ? bk[o3 - 768] : bv[o3 - 1536]);
    bqkv[o3] = v;
  }
}

// QKV projection, 256x256 8-wave core (r10-proven): qkvb = bf16(x@[Wq|Wk|Wv]+b).
// grid 1152 = 128 bm x 9 bn (bn-fast).
__global__ __launch_bounds__(512, 2) void k_gemm_qkv(
    const unsigned short* __restrict__ xb, const unsigned short* __restrict__ wT,
    const float* __restrict__ bqkv, unsigned short* __restrict__ qkvb)
{
  __shared__ unsigned short As[2 * QT], Bs[2 * QT];   // 128 KiB
  int bx = blockIdx.x, bn = bx % 9, bm = bx / 9;
  f32x4 acc[8][4]; ACC_ZERO8(acc);
  gemm256_core(xb + (size_t)bm * 256 * 768, 768, wT + (size_t)bn * 256 * 768, 768,
               768, As, Bs, acc);
  const int lane = threadIdx.x & 63, wid = threadIdx.x >> 6;
  const int wr = wid >> 2, wc = wid & 3, lr = lane & 15, kg = lane >> 4;
#pragma unroll
  for (int mi = 0; mi < 8; ++mi)
#pragma unroll
    for (int ni = 0; ni < 4; ++ni) {
      int col = bn * 256 + wc * 64 + ni * 16 + lr;
      float bias = bqkv[col];
#pragma unroll
      for (int e = 0; e < 4; ++e) {
        int row = bm * 256 + wr * 128 + mi * 16 + kg * 4 + e;   // token
        qkvb[(size_t)row * 2304 + col] = f2bf(acc[mi][ni][e] + bias);
      }
    }
}

// MERGED scores + repack_v (both only READ qkvb; disjoint outputs Sp / Vb).
// Blocks 0..383: scores split-K x4 (r5-proven gather-staged form).
// Blocks 384..6527: V repack via LDS 64x64 transpose.
// Scores first: they are the critical-path consumer-feeders.
__global__ __launch_bounds__(256) void k_scores_repack(
    const unsigned short* __restrict__ qkvb, float* __restrict__ Spart,
    unsigned short* __restrict__ V)
{
  __shared__ unsigned short Asp[128 * LDP], Bsp[128 * LDP];
  int b = blockIdx.x;
  if (b < 384) {
    int s = b / 96, rblk = b % 96;
    int hn = rblk >> 2, tt = rblk & 3, bm = tt >> 1, bn = tt & 1;
    int h = hn >> 1, nn = hn & 1;
    const int hq = h * 64;
    f32x4 acc[4][4]; ACC_ZERO(acc);

    const int tid = threadIdx.x, lane = tid & 63, wid = tid >> 6;
    const int wr = wid >> 1, wc = wid & 1, lr = lane & 15, kg = lane >> 4;
    const int srow = tid >> 3, sch = tid & 7;

    for (int t = 0; t < 16; ++t) {
      int rr = s * 16 + t;
      us8 av[4], bv[4];
#pragma unroll
      for (int c = 0; c < 4; ++c) {
        int row = c * 32 + srow;
        size_t ab = ((size_t)((rr * 256 + bm * 128 + row) * 2 + nn)) * 2304 + hq + sch * 8;
        size_t bb = ((size_t)((rr * 256 + bn * 128 + row) * 2 + nn)) * 2304 + 768 + hq + sch * 8;
        av[c] = *reinterpret_cast<const us8*>(qkvb + ab);
        bv[c] = *reinterpret_cast<const us8*>(qkvb + bb);
      }
      __syncthreads();
#pragma unroll
      for (int c = 0; c < 4; ++c) {
        int row = c * 32 + srow;
        *reinterpret_cast<us8*>(Asp + row * LDP + sch * 8) = av[c];
        *reinterpret_cast<us8*>(Bsp + row * LDP + sch * 8) = bv[c];
      }
      __syncthreads();
#pragma unroll
      for (int ks = 0; ks < 2; ++ks) {
        bf16x8 af[4], bfr[4];
#pragma unroll
        for (int mi = 0; mi < 4; ++mi)
          af[mi] = *reinterpret_cast<const bf16x8*>(Asp + (wr*64 + mi*16 + lr) * LDP + ks*32 + kg*8);
#pragma unroll
        for (int ni = 0; ni < 4; ++ni)
          bfr[ni] = *reinterpret_cast<const bf16x8*>(Bsp + (wc*64 + ni*16 + lr) * LDP + ks*32 + kg*8);
#pragma unroll
        for (int mi = 0; mi < 4; ++mi)
#pragma unroll
          for (int ni = 0; ni < 4; ++ni)
            acc[mi][ni] = __builtin_amdgcn_mfma_f32_16x16x32_bf16(af[mi], bfr[ni], acc[mi][ni], 0, 0, 0);
      }
    }

    float* Ss = Spart + ((size_t)s * 24 + hn) * 65536;
#pragma unroll
    for (int mi = 0; mi < 4; ++mi)
#pragma unroll
      for (int ni = 0; ni < 4; ++ni)
#pragma unroll
        for (int e = 0; e < 4; ++e) {
          int row = bm * 128 + wr * 64 + mi * 16 + kg * 4 + e;
          int col = bn * 128 + wc * 64 + ni * 16 + lr;
          Ss[(size_t)row * 256 + col] = acc[mi][ni][e];
        }
    return;
  }

  // ---- V repack branch (uses the same LDS, different shape view) ----
  unsigned short* lds = Asp;   // 64*LDP = 5120 elems < 128*LDP
  int bx = b - 384;
  int jt = bx & 3, rr = (bx >> 2) & 63, hn = bx >> 8;
  int h = hn >> 1, nn = hn & 1;
  int t = threadIdx.x;
  int j = t >> 3, ch = t & 7;
#pragma unroll
  for (int p = 0; p < 2; ++p) {
    int jj = p * 32 + j;
    us8 v = *reinterpret_cast<const us8*>(
        qkvb + ((size_t)((rr * 256 + jt * 64 + jj) * 2 + nn)) * 2304 + 1536 + h * 64 + ch * 8);
#pragma unroll
    for (int e = 0; e < 8; ++e) lds[(ch * 8 + e) * LDP + jj] = v[e];
  }
  __syncthreads();
  int dd = t >> 2, cj = t & 3;
  size_t ob = ((size_t)(hn * 64 + rr) * 64) * 256;
#pragma unroll
  for (int p = 0; p < 2; ++p) {
    int c2 = cj + p * 4;
    us8 v = *reinterpret_cast<const us8*>(lds + dd * LDP + c2 * 8);
    *reinterpret_cast<us8*>(V + ob + (size_t)dd * 256 + jt * 64 + c2 * 8) = v;
  }
}

// Row softmax over j=256 with 4-way split-K reduction. grid 6144.
__global__ __launch_bounds__(256) void k_softmax(const float* __restrict__ Sp,
                                                 unsigned short* __restrict__ P)
{
  __shared__ float red[8];
  size_t row = blockIdx.x;
  int t = threadIdx.x, wid = t >> 6, lane = t & 63;
  size_t idx = row * 256 + t;
  float v = Sp[idx] + Sp[idx + 1572864] + Sp[idx + 2 * 1572864] + Sp[idx + 3 * 1572864];
  float m = v;
#pragma unroll
  for (int o = 32; o; o >>= 1) m = fmaxf(m, __shfl_xor(m, o));
  if (lane == 0) red[wid] = m;
  __syncthreads();
  m = fmaxf(fmaxf(red[0], red[1]), fmaxf(red[2], red[3]));
  float e = __expf(v - m);
  float sm = e;
#pragma unroll
  for (int o = 32; o; o >>= 1) sm += __shfl_xor(sm, o);
  if (lane == 0) red[4 + wid] = sm;
  __syncthreads();
  sm = red[4] + red[5] + red[6] + red[7];
  P[row * 256 + t] = f2bf(e / sm);
}

// Context: per (h,n): C2[i][c=(rr,dd)] = sum_j P[i][j] V[c][j]; scatter to Cb.
// grid 1536 (no swizzle).
__global__ __launch_bounds__(256) void k_gemm_ctx(
    const unsigned short* __restrict__ P, const unsigned short* __restrict__ V,
    unsigned short* __restrict__ Cb)
{
  GEMM_LDS;
  int bx = blockIdx.x;
  int hn = bx / 64, tt = bx % 64, bm = tt >> 5, bn = tt & 31;
  f32x4 acc[4][4]; ACC_ZERO(acc);
  const unsigned short* Ag = P + (size_t)hn * 65536 + (size_t)bm * 128 * 256;
  const unsigned short* Bg = V + (size_t)hn * 4096 * 256 + (size_t)bn * 128 * 256;
  gemm_core(Ag, 256, Bg, 256, 256, As, Bs, acc);
  EPI_VARS;
  int nn = hn & 1;
  int h = hn >> 1;
#pragma unroll
  for (int mi = 0; mi < 4; ++mi)
#pragma unroll
    for (int ni = 0; ni < 4; ++ni) {
      int c = bn * 128 + wc * 64 + ni * 16 + lr;   // rr*64+dd
      int rr = c >> 6, dd = c & 63;
#pragma unroll
      for (int e = 0; e < 4; ++e) {
        int i = bm * 128 + wr * 64 + mi * 16 + kg * 4 + e;
        int tok = (rr * 256 + i) * 2 + nn;
        Cb[(size_t)tok * 768 + h * 64 + dd] = f2bf(acc[mi][ni][e]);
      }
    }
}

// Output projection (r8-proven 128x128 core): out = C @ Wo + bo (fp32).
// grid 1536, XCD-swizzled.
__global__ __launch_bounds__(256) void k_gemm_out(
    const unsigned short* __restrict__ Cb, const unsigned short* __restrict__ woT,
    const float* __restrict__ bo, float* __restrict__ out)
{
  GEMM_LDS;
  int b0 = blockIdx.x;
  int bx = (b0 & 7) * 192 + (b0 >> 3);     // bijective (1536 % 8 == 0)
  int bn = bx % 6, bm = bx / 6;
  f32x4 acc[4][4]; ACC_ZERO(acc);
  gemm_core(Cb + (size_t)bm * 128 * 768, 768, woT + (size_t)bn * 128 * 768, 768, 768, As, Bs, acc);
  EPI_VARS;
#pragma unroll
  for (int mi = 0; mi < 4; ++mi)
#pragma unroll
    for (int ni = 0; ni < 4; ++ni) {
      int col = bn * 128 + wc * 64 + ni * 16 + lr;
      float bias = bo[col];
#pragma unroll
      for (int e = 0; e < 4; ++e) {
        int row = bm * 128 + wr * 64 + mi * 16 + kg * 4 + e;
        out[(size_t)row * 768 + col] = acc[mi][ni][e] + bias;
      }
    }
}

// ======================================================================
extern "C" void kernel_launch(void* const* d_in, const int* in_sizes, int n_in,
                              void* d_out, int out_size, void* d_ws, size_t ws_size,
                              hipStream_t stream)
{
  const float* x  = (const float*)d_in[0];
  const float* Wq = (const float*)d_in[1];
  const float* bq = (const float*)d_in[2];
  const float* Wk = (const float*)d_in[3];
  const float* bk = (const float*)d_in[4];
  const float* Wv = (const float*)d_in[5];
  const float* bv = (const float*)d_in[6];
  const float* Wo = (const float*)d_in[7];
  const float* bo = (const float*)d_in[8];
  float* out = (float*)d_out;

  char* ws = (char*)d_ws;
  size_t off = 0;
  auto alloc = [&](size_t bytes) { void* p = ws + off; off += (bytes + 255) & ~(size_t)255; return p; };
  unsigned short* xb   = (unsigned short*)alloc(50331648);   // x bf16 [t][768]
  unsigned short* qkvb = (unsigned short*)alloc(150994944);  // [t][2304] bf16
  unsigned short* Vb   = (unsigned short*)alloc(50331648);   // V [hn][4096][256]
  unsigned short* Cb   = (unsigned short*)alloc(50331648);   // context [t][768] bf16
  unsigned short* wT   = (unsigned short*)alloc(3538944);    // [2304][768] bf16
  unsigned short* woT  = (unsigned short*)alloc(1179648);    // [768][768] bf16
  float*          bqkv = (float*)alloc(9216);
  if (off > ws_size) return;

  // Scores partials + probs live in d_out (28.3MB of 100.6MB); both are fully
  // consumed by k_gemm_ctx before k_gemm_out overwrites d_out with the result.
  float*          Sp = (float*)d_out;                                   // [4][hn][256][256] f32
  unsigned short* P  = (unsigned short*)((char*)d_out + 25165824);      // [hn][256][256] bf16

  k_cvt_xw       <<<33801, 256, 0, stream>>>(x, xb, Wq, Wk, Wv, Wo, bq, bk, bv, wT, woT, bqkv);
  k_gemm_qkv     <<<1152,  512, 0, stream>>>(xb, wT, bqkv, qkvb);
  k_scores_repack<<<6528,  256, 0, stream>>>(qkvb, Sp, Vb);
  k_softmax      <<<6144,  256, 0, stream>>>(Sp, P);
  k_gemm_ctx     <<<1536,  256, 0, stream>>>(P, Vb, Cb);
  k_gemm_out     <<<1536,  256, 0, stream>>>(Cb, woT, bo, out);
}